// Round 5
// baseline (1112.530 us; speedup 1.0000x reference)
//
#include <hip/hip_runtime.h>
#include <cstdint>
#include <cstddef>

// Problem constants (from reference)
#define B_    2
#define S_    4096
#define H_    2048
#define D2_   1024
#define SCALE_ 0.125f

typedef __attribute__((ext_vector_type(8))) _Float16 half8;
typedef __attribute__((ext_vector_type(4))) float f32x4;
typedef __attribute__((ext_vector_type(16))) float f32x16;

__device__ __forceinline__ ushort f2h(float f) {
    _Float16 h = (_Float16)f;
    return *(ushort*)&h;
}
__device__ __forceinline__ float h2f(ushort u) {
    return (float)(*(_Float16*)&u);
}

// async 16B global -> LDS (wave-uniform base + lane*16 semantics)
__device__ __forceinline__ void gld_lds16(const ushort* g, ushort* l) {
    __builtin_amdgcn_global_load_lds((const __attribute__((address_space(1))) void*)g,
                                     (__attribute__((address_space(3))) void*)l,
                                     16, 0, 0);
}

// ---------------- elementwise cast fp32 -> fp16, n4 = n/4 ----------------
__global__ __launch_bounds__(256) void cast_f16_kernel(const float* __restrict__ src,
                                                       ushort* __restrict__ dst, int n4) {
    int i = blockIdx.x * 256 + threadIdx.x;
    if (i < n4) {
        float4 v = ((const float4*)src)[i];
        ushort4 o;
        o.x = f2h(v.x); o.y = f2h(v.y); o.z = f2h(v.z); o.w = f2h(v.w);
        ((ushort4*)dst)[i] = o;
    }
}

__global__ __launch_bounds__(256) void cast4_f16_kernel(const float* __restrict__ w0,
                                                        const float* __restrict__ w1,
                                                        const float* __restrict__ w2,
                                                        const float* __restrict__ w3,
                                                        ushort* __restrict__ o0,
                                                        ushort* __restrict__ o1,
                                                        ushort* __restrict__ o2,
                                                        ushort* __restrict__ o3,
                                                        int n4) {
    int i = blockIdx.x * 256 + threadIdx.x;
    if (i >= n4) return;
    const float* s; ushort* d;
    switch (blockIdx.y) {
        case 0: s = w0; d = o0; break;
        case 1: s = w1; d = o1; break;
        case 2: s = w2; d = o2; break;
        default: s = w3; d = o3; break;
    }
    float4 v = ((const float4*)s)[i];
    ushort4 o;
    o.x = f2h(v.x); o.y = f2h(v.y); o.z = f2h(v.z); o.w = f2h(v.w);
    ((ushort4*)d)[i] = o;
}

// =================================================================================
// gemm256: C[M,N] = alpha * A[M,K] * B[N,K]^T, f16 in, f32/f16 out.
// 256x256 tile, BK=64, 512 threads = 8 waves (2M x 4N), per-wave 128x64 output.
// 32x32x16 f16 MFMA (half the instruction count of 16x16x32, same LDS bytes).
//   A frag: row = lane&31, k = (lane>>5)*8 + [0..8)   (one ds_read_b128)
//   B frag: col = lane&31, k = (lane>>5)*8 + [0..8)
//   C/D:    col = lane&31, row = (reg&3) + 8*(reg>>2) + 4*(lane>>5)  [m74/m101]
// Round-4 X/Y schedule kept (2 barriers + 2 counted vmcnt(4) per tile, reads
// one region ahead of use, staging one tile ahead). Tile loop unrolled x2 so
// the LDS double-buffer parity is compile-time: all ds_read addresses are
// 8 precomputed per-lane base pointers + immediate offsets (no per-tile VALU).
// XOR-swizzled LDS (T2), setprio on MFMA clusters (T5), XCD swizzle (T1).
// =================================================================================
#define WAIT_VM(N) asm volatile("s_waitcnt vmcnt(" #N ")" ::: "memory")
#define BAR        asm volatile("s_barrier" ::: "memory")

template <int BUF, int QM>
__device__ __forceinline__ void ldA(const ushort* const (&aP)[4], half8 (&af)[2][4]) {
#pragma unroll
    for (int m2 = 0; m2 < 2; m2++)
#pragma unroll
        for (int ks = 0; ks < 4; ks++)
            af[m2][ks] = *(const half8*)(aP[ks] + BUF * 16384 + (QM * 2 + m2) * 2048);
}
template <int BUF, int QN>
__device__ __forceinline__ void ldB(const ushort* const (&bP)[4], half8 (&bf)[4]) {
#pragma unroll
    for (int ks = 0; ks < 4; ks++)
        bf[ks] = *(const half8*)(bP[ks] + BUF * 16384 + QN * 2048);
}
template <int QM, int QN>
__device__ __forceinline__ void mma32(const half8 (&af)[2][4], const half8 (&bf)[4],
                                      f32x16 (&acc)[4][2]) {
    __builtin_amdgcn_s_setprio(1);
#pragma unroll
    for (int ks = 0; ks < 4; ks++)
#pragma unroll
        for (int m2 = 0; m2 < 2; m2++)
            acc[QM * 2 + m2][QN] = __builtin_amdgcn_mfma_f32_32x32x16_f16(
                af[m2][ks], bf[ks], acc[QM * 2 + m2][QN], 0, 0, 0);
    __builtin_amdgcn_s_setprio(0);
}

// One K-tile: X { vm(4)[A(t) landed] BAR | read af0(t) | stage A(t+1) |
//                 mma q10(t-1) }
//             Y { vm(4)[B(t) landed] BAR | mma q11(t-1) | read bf0,bf1(t) |
//                 stage B(t+1) | read af1(t) | mma q00(t) q01(t) }
#define TILE_STEP(T_, BUF_, STG_, LASTY_, DOPREV_)                      \
    {                                                                   \
        WAIT_VM(4);                                                     \
        BAR;                                                            \
        ldA<BUF_, 0>(aP, af0);                                          \
        if (STG_) { stA((T_) + 1, 0); stA((T_) + 1, 1); }               \
        if (DOPREV_) mma32<1, 0>(af1, bf0, acc);                        \
        if (LASTY_) { WAIT_VM(0); } else { WAIT_VM(4); }                \
        BAR;                                                            \
        if (DOPREV_) mma32<1, 1>(af1, bf1, acc);                        \
        ldB<BUF_, 0>(bP, bf0);                                          \
        ldB<BUF_, 1>(bP, bf1);                                          \
        if (STG_) { stB((T_) + 1, 0); stB((T_) + 1, 1); }               \
        ldA<BUF_, 1>(aP, af1);                                          \
        mma32<0, 0>(af0, bf0, acc);                                     \
        mma32<0, 1>(af0, bf1, acc);                                     \
    }

template <bool HALF_OUT>
__global__ __launch_bounds__(512, 1) void gemm256(const ushort* __restrict__ A,
                                                  const ushort* __restrict__ B,
                                                  void* __restrict__ Cv,
                                                  int M, int N, int K, float alpha,
                                                  size_t sA, size_t sB, size_t sC) {
    __shared__ __align__(16) ushort As[2][256][64];   // 64 KB
    __shared__ __align__(16) ushort Bs[2][256][64];   // 64 KB

    A += (size_t)blockIdx.z * sA;
    B += (size_t)blockIdx.z * sB;

    // T1: bijective XCD swizzle over the flattened 2D grid (nwg % 8 == 0 always here)
    const int nwg  = gridDim.x * gridDim.y;
    const int orig = blockIdx.y * gridDim.x + blockIdx.x;
    const int wg   = (orig & 7) * (nwg >> 3) + (orig >> 3);
    const int bm   = (wg / gridDim.x) * 256;
    const int bn   = (wg % gridDim.x) * 256;

    const int tid  = threadIdx.x;
    const int lane = tid & 63;
    const int wave = tid >> 6;     // 0..7
    const int wr   = wave >> 2;    // 0..1 -> 128-row half
    const int wc   = wave & 3;     // 0..3 -> 64-col slice
    const int r32  = lane & 31;
    const int kh   = lane >> 5;    // k-octet
    const int xk   = r32 & 7;      // XOR swizzle key (row&7; row bases are x32)

    // ---- staging: chunk = tid (rows 0..63 of half) and tid+512 (rows 64..127).
    // Inverse-swizzled global source: row r keeps its row, 16B-col = (c&7) ^ (r&7).
    const int srow = tid >> 3;                           // 0..63
    const int scol = ((tid & 7) ^ (srow & 7)) * 8;       // swizzled 16B column (elems)
    const ushort* gA = A + (size_t)(bm + srow) * K + scol;
    const ushort* gB = B + (size_t)(bn + srow) * K + scol;
    const size_t rs64  = (size_t)64 * K;
    const size_t rs128 = (size_t)128 * K;
    ushort* lA = &As[0][0][0] + tid * 8;                 // linear dest, byte tid*16
    ushort* lB = &Bs[0][0][0] + tid * 8;

    auto stA = [&](int t, int h) {
        const ushort* s = gA + (size_t)t * 64 + (h ? rs128 : (size_t)0);
        ushort* d = lA + ((t & 1) << 14) + (h << 13);
        gld_lds16(s, d);
        gld_lds16(s + rs64, d + 4096);
    };
    auto stB = [&](int t, int h) {
        const ushort* s = gB + (size_t)t * 64 + (h ? rs128 : (size_t)0);
        ushort* d = lB + ((t & 1) << 14) + (h << 13);
        gld_lds16(s, d);
        gld_lds16(s + rs64, d + 4096);
    };

    // ---- precomputed per-lane LDS read pointers (swizzled); mt/nt/BUF via imm
    int kq[4];
#pragma unroll
    for (int ks = 0; ks < 4; ks++) kq[ks] = ((ks * 2 + kh) ^ xk) * 8;
    const ushort* aP[4];
    const ushort* bP[4];
#pragma unroll
    for (int ks = 0; ks < 4; ks++) {
        aP[ks] = &As[0][0][0] + (wr * 128 + r32) * 64 + kq[ks];
        bP[ks] = &Bs[0][0][0] + (wc * 64 + r32) * 64 + kq[ks];
    }

    f32x16 acc[4][2];
#pragma unroll
    for (int i = 0; i < 4; i++)
#pragma unroll
        for (int j = 0; j < 2; j++)
#pragma unroll
            for (int r = 0; r < 16; r++) acc[i][j][r] = 0.f;

    half8 af0[2][4], af1[2][4], bf0[4], bf1[4];

    const int T  = K >> 6;   // K-tiles (K = 2048 or 4096 -> T = 32 or 64, even)
    const int TP = T >> 1;

    // prologue: issue tile-0 staging (A first, then B -- wait order relies on this)
    stA(0, 0); stA(0, 1); stB(0, 0); stB(0, 1);

    for (int p = 0; p < TP; ++p) {
        const int t0 = 2 * p;
        TILE_STEP(t0,     0, true,        false,       t0 > 0);
        TILE_STEP(t0 + 1, 1, p + 1 < TP,  p + 1 == TP, true);
    }
    // drain last tile's second A-half quadrants
    mma32<1, 0>(af1, bf0, acc);
    mma32<1, 1>(af1, bf1, acc);

    // ---- epilogue: C/D col = lane&31, row = (reg&3)+8*(reg>>2)+4*kh [m74/m101]
    ushort* Ch = (ushort*)Cv + (size_t)blockIdx.z * sC;
    float*  Cf = (float*)Cv + (size_t)blockIdx.z * sC;
#pragma unroll
    for (int mt = 0; mt < 4; mt++)
#pragma unroll
        for (int nt = 0; nt < 2; nt++) {
            const int gcol = bn + wc * 64 + nt * 32 + r32;
#pragma unroll
            for (int reg = 0; reg < 16; reg++) {
                int grow = bm + wr * 128 + mt * 32 + (reg & 3) + 8 * (reg >> 2) + 4 * kh;
                float val = alpha * acc[mt][nt][reg];
                if (HALF_OUT)
                    Ch[(size_t)grow * N + gcol] = f2h(val);
                else
                    Cf[(size_t)grow * N + gcol] = val;
            }
        }
}

// ---------------- RoPE: f16 q,k in; interleaved f16 q_rot/k_rot + fp32 k_rot ------
__global__ __launch_bounds__(256) void rope_kernel(const ushort* __restrict__ qh,
                                                   const ushort* __restrict__ kh,
                                                   const float* __restrict__ cosT,
                                                   const float* __restrict__ sinT,
                                                   const int* __restrict__ pos,
                                                   ushort* __restrict__ qr,
                                                   ushort* __restrict__ kr,
                                                   float* __restrict__ krf32) {
    int idx = blockIdx.x * 256 + threadIdx.x;       // B*S*(D2/4) total
    int row = idx >> 8;                             // D2_/4 == 256
    int jj  = (idx & 255) * 4;
    int p = pos[row & (S_ - 1)];
    const ushort* q = qh + (size_t)row * H_ + jj;
    const ushort* k = kh + (size_t)row * H_ + jj;
    const float* cr = cosT + (size_t)p * D2_ + jj;
    const float* sr = sinT + (size_t)p * D2_ + jj;
    float4 c = *(const float4*)cr;
    float4 sn = *(const float4*)sr;
    ushort4 qr4 = *(const ushort4*)q;
    ushort4 qi4 = *(const ushort4*)(q + D2_);
    ushort4 kr4 = *(const ushort4*)k;
    ushort4 ki4 = *(const ushort4*)(k + D2_);

    float qrv[4] = {h2f(qr4.x), h2f(qr4.y), h2f(qr4.z), h2f(qr4.w)};
    float qiv[4] = {h2f(qi4.x), h2f(qi4.y), h2f(qi4.z), h2f(qi4.w)};
    float krv[4] = {h2f(kr4.x), h2f(kr4.y), h2f(kr4.z), h2f(kr4.w)};
    float kiv[4] = {h2f(ki4.x), h2f(ki4.y), h2f(ki4.z), h2f(ki4.w)};
    float cv[4] = {c.x, c.y, c.z, c.w};
    float sv[4] = {sn.x, sn.y, sn.z, sn.w};

    ushort qo[8], ko[8];
    float kf[8];
#pragma unroll
    for (int t = 0; t < 4; t++) {
        float o0 = qrv[t] * cv[t] - qiv[t] * sv[t];
        float o1 = qrv[t] * sv[t] + qiv[t] * cv[t];
        qo[2 * t] = f2h(o0); qo[2 * t + 1] = f2h(o1);
        float p0 = krv[t] * cv[t] - kiv[t] * sv[t];
        float p1 = krv[t] * sv[t] + kiv[t] * cv[t];
        ko[2 * t] = f2h(p0); ko[2 * t + 1] = f2h(p1);
        kf[2 * t] = p0; kf[2 * t + 1] = p1;
    }
    ushort* qro = qr + (size_t)row * H_ + 2 * jj;
    ushort* kro = kr + (size_t)row * H_ + 2 * jj;
    float* krf  = krf32 + (size_t)row * H_ + 2 * jj;
    *(ushort4*)(qro)     = *(ushort4*)(qo);
    *(ushort4*)(qro + 4) = *(ushort4*)(qo + 4);
    *(ushort4*)(kro)     = *(ushort4*)(ko);
    *(ushort4*)(kro + 4) = *(ushort4*)(ko + 4);
    *(float4*)(krf)      = *(float4*)(kf);
    *(float4*)(krf + 4)  = *(float4*)(kf + 4);
}

// ---------------- transpose+cast: v[b][s][h] fp32 -> vt[b][h][s] f16 ------------
__global__ __launch_bounds__(256) void transpose_cast_kernel(const float* __restrict__ v,
                                                             ushort* __restrict__ vt) {
    __shared__ float tile[32][33];
    int b  = blockIdx.z;
    int s0 = blockIdx.y * 32, h0 = blockIdx.x * 32;
    const float* vb = v + (size_t)b * S_ * H_;
    ushort* vtb = vt + (size_t)b * H_ * S_;
    int tx = threadIdx.x & 31, ty = threadIdx.x >> 5;
#pragma unroll
    for (int i = 0; i < 32; i += 8)
        tile[ty + i][tx] = vb[(size_t)(s0 + ty + i) * H_ + h0 + tx];
    __syncthreads();
#pragma unroll
    for (int i = 0; i < 32; i += 8)
        vtb[(size_t)(h0 + ty + i) * S_ + s0 + tx] = f2h(tile[tx][ty + i]);
}

// ---------------- row softmax: f16 scores (4096 wide) -> f16 probs --------------
__global__ __launch_bounds__(256) void softmax_kernel(const ushort* __restrict__ sc,
                                                      ushort* __restrict__ pr) {
    __shared__ float red[8];
    size_t row = blockIdx.x;
    const uint4* r = (const uint4*)(sc + row * (size_t)S_);   // 512 x 16B per row
    int tid = threadIdx.x;
    uint4 v0 = r[tid], v1 = r[tid + 256];
    uint w[8] = {v0.x, v0.y, v0.z, v0.w, v1.x, v1.y, v1.z, v1.w};
    float f[16];
#pragma unroll
    for (int i = 0; i < 8; i++) {
        f[2 * i]     = h2f((ushort)(w[i] & 0xffffu));
        f[2 * i + 1] = h2f((ushort)(w[i] >> 16));
    }
    float m = -1e30f;
#pragma unroll
    for (int i = 0; i < 16; i++) m = fmaxf(m, f[i]);
#pragma unroll
    for (int off = 32; off >= 1; off >>= 1) m = fmaxf(m, __shfl_xor(m, off));
    if ((tid & 63) == 0) red[tid >> 6] = m;
    __syncthreads();
    m = fmaxf(fmaxf(red[0], red[1]), fmaxf(red[2], red[3]));
    float s = 0.f;
#pragma unroll
    for (int i = 0; i < 16; i++) { f[i] = __expf(f[i] - m); s += f[i]; }
#pragma unroll
    for (int off = 32; off >= 1; off >>= 1) s += __shfl_xor(s, off);
    if ((tid & 63) == 0) red[4 + (tid >> 6)] = s;
    __syncthreads();
    float inv = 1.0f / (red[4] + red[5] + red[6] + red[7]);
    uint o[8];
#pragma unroll
    for (int i = 0; i < 8; i++)
        o[i] = (uint)f2h(f[2 * i] * inv) | ((uint)f2h(f[2 * i + 1] * inv) << 16);
    uint4* op = (uint4*)(pr + row * (size_t)S_);
    uint4 u0, u1;
    u0.x = o[0]; u0.y = o[1]; u0.z = o[2]; u0.w = o[3];
    u1.x = o[4]; u1.y = o[5]; u1.z = o[6]; u1.w = o[7];
    op[tid] = u0;
    op[tid + 256] = u1;
}

// =================================================================================
extern "C" void kernel_launch(void* const* d_in, const int* in_sizes, int n_in,
                              void* d_out, int out_size, void* d_ws, size_t ws_size,
                              hipStream_t stream) {
    const float* hs   = (const float*)d_in[0];
    const float* wq   = (const float*)d_in[1];
    const float* wk   = (const float*)d_in[2];
    const float* wv   = (const float*)d_in[3];
    const float* wo   = (const float*)d_in[4];
    const float* fcos = (const float*)d_in[5];
    const float* fsin = (const float*)d_in[6];
    const int*   pos  = (const int*)d_in[7];

    const size_t BSH = (size_t)B_ * S_ * H_;   // 16,777,216
    const size_t HH  = (size_t)H_ * H_;        //  4,194,304

    float* out      = (float*)d_out;           // [0] output (B,S,H)
    float* krot_out = out + BSH;               // [1] k_rot  (B,S,H)
    float* v_out    = krot_out + BSH;          // [2] v      (B,S,H)

    char* ws = (char*)d_ws;
    const size_t MB = 1ull << 20;
    ushort* Xb  = (ushort*)(ws + 0);
    ushort* Wqb = (ushort*)(ws + 32 * MB);
    ushort* Wkb = (ushort*)(ws + 40 * MB);
    ushort* Wvb = (ushort*)(ws + 48 * MB);
    ushort* Wob = (ushort*)(ws + 56 * MB);
    ushort* qh  = (ushort*)(ws + 64 * MB);
    ushort* kh  = (ushort*)(ws + 96 * MB);
    ushort* qrb = (ushort*)(ws + 128 * MB);
    ushort* krb = (ushort*)(ws + 160 * MB);
    ushort* vtb = (ushort*)(ws + 192 * MB);
    ushort* sc  = (ushort*)(ws + 224 * MB);    // f16 scores (67 MB)
    ushort* prb = (ushort*)(ws + 64 * MB);     // reuse qh+kh (dead after rope)
    ushort* cb  = (ushort*)(ws + 128 * MB);    // reuse qrb (dead after scores)

    // 1. casts to f16
    cast_f16_kernel<<<(int)(BSH / 4 / 256), 256, 0, stream>>>(hs, Xb, (int)(BSH / 4));
    cast4_f16_kernel<<<dim3((int)(HH / 4 / 256), 4), 256, 0, stream>>>(
        wq, wk, wv, wo, Wqb, Wkb, Wvb, Wob, (int)(HH / 4));

    // 2. Q/K/V projections (C = X * W^T); Q/K straight to f16, V to fp32 output
    dim3 gProj(H_ / 256, (B_ * S_) / 256, 1);  // (8, 32) = 256 blocks
    gemm256<true ><<<gProj, 512, 0, stream>>>(Xb, Wqb, qh,    B_ * S_, H_, H_, 1.0f, 0, 0, 0);
    gemm256<true ><<<gProj, 512, 0, stream>>>(Xb, Wkb, kh,    B_ * S_, H_, H_, 1.0f, 0, 0, 0);
    gemm256<false><<<gProj, 512, 0, stream>>>(Xb, Wvb, v_out, B_ * S_, H_, H_, 1.0f, 0, 0, 0);

    // 3. RoPE (f16 q_rot/k_rot for attention + fp32 k_rot output)
    rope_kernel<<<(B_ * S_ * (D2_ / 4)) / 256, 256, 0, stream>>>(
        qh, kh, fcos, fsin, pos, qrb, krb, krot_out);

    // 4. v^T in f16 for the PV GEMM
    transpose_cast_kernel<<<dim3(H_ / 32, S_ / 32, B_), 256, 0, stream>>>(v_out, vtb);

    // 5. scores = SCALE * q_rot k_rot^T, f16 out, both batches in one launch (z)
    dim3 gSc(S_ / 256, S_ / 256, B_);          // (16, 16, 2)
    gemm256<true><<<gSc, 512, 0, stream>>>(qrb, krb, sc, S_, S_, H_, SCALE_,
                                           (size_t)S_ * H_, (size_t)S_ * H_,
                                           (size_t)S_ * S_);

    // 6. softmax rows (f16 in) -> f16 probs
    softmax_kernel<<<B_ * S_, 256, 0, stream>>>(sc, prb);

    // 7. ctx = probs @ v (as probs * (v^T)^T), f16 out, both batches via z
    dim3 gPV(H_ / 256, S_ / 256, B_);          // (8, 16, 2) = 256 blocks
    gemm256<true><<<gPV, 512, 0, stream>>>(prb, vtb, cb, S_, H_, S_, 1.0f,
                                           (size_t)S_ * S_, (size_t)H_ * S_,
                                           (size_t)S_ * H_);

    // 8. output projection
    gemm256<false><<<gProj, 512, 0, stream>>>(cb, Wob, out, B_ * S_, H_, H_, 1.0f, 0, 0, 0);
}

// Round 7
// 1076.597 us; speedup vs baseline: 1.0334x; 1.0334x over previous
//
#include <hip/hip_runtime.h>
#include <cstdint>
#include <cstddef>

// Problem constants (from reference)
#define B_    2
#define S_    4096
#define H_    2048
#define D2_   1024
#define SCALE_ 0.125f

typedef __attribute__((ext_vector_type(8))) _Float16 half8;
typedef __attribute__((ext_vector_type(4))) float f32x4;

__device__ __forceinline__ ushort f2h(float f) {
    _Float16 h = (_Float16)f;
    return *(ushort*)&h;
}
__device__ __forceinline__ float h2f(ushort u) {
    return (float)(*(_Float16*)&u);
}

// async 16B global -> LDS (wave-uniform base + lane*16 semantics)
__device__ __forceinline__ void gld_lds16(const ushort* g, ushort* l) {
    __builtin_amdgcn_global_load_lds((const __attribute__((address_space(1))) void*)g,
                                     (__attribute__((address_space(3))) void*)l,
                                     16, 0, 0);
}

// ---------------- elementwise cast fp32 -> fp16, n4 = n/4 ----------------
__global__ __launch_bounds__(256) void cast_f16_kernel(const float* __restrict__ src,
                                                       ushort* __restrict__ dst, int n4) {
    int i = blockIdx.x * 256 + threadIdx.x;
    if (i < n4) {
        float4 v = ((const float4*)src)[i];
        ushort4 o;
        o.x = f2h(v.x); o.y = f2h(v.y); o.z = f2h(v.z); o.w = f2h(v.w);
        ((ushort4*)dst)[i] = o;
    }
}

__global__ __launch_bounds__(256) void cast4_f16_kernel(const float* __restrict__ w0,
                                                        const float* __restrict__ w1,
                                                        const float* __restrict__ w2,
                                                        const float* __restrict__ w3,
                                                        ushort* __restrict__ o0,
                                                        ushort* __restrict__ o1,
                                                        ushort* __restrict__ o2,
                                                        ushort* __restrict__ o3,
                                                        int n4) {
    int i = blockIdx.x * 256 + threadIdx.x;
    if (i >= n4) return;
    const float* s; ushort* d;
    switch (blockIdx.y) {
        case 0: s = w0; d = o0; break;
        case 1: s = w1; d = o1; break;
        case 2: s = w2; d = o2; break;
        default: s = w3; d = o3; break;
    }
    float4 v = ((const float4*)s)[i];
    ushort4 o;
    o.x = f2h(v.x); o.y = f2h(v.y); o.z = f2h(v.z); o.w = f2h(v.w);
    ((ushort4*)d)[i] = o;
}

// =================================================================================
// gemm256: C[M,N] = alpha * A[M,K] * B[N,K]^T, f16 in, f32/f16 out.
// ROUND-4 CORE (verified: 131us scores, 0 bank conflicts, MfmaUtil 46%):
// 256x256 tile, BK=64, 512 threads = 8 waves (2M x 4N), 16x16x32 f16 MFMA,
// X/Y two-region schedule, 2 barriers + 2 counted vmcnt(4) per K-tile, reads
// one region ahead of use, staging one tile ahead, XOR-swizzled LDS (T2),
// setprio (T5), XCD swizzle (T1).
// NEW vs round 4: per-lane LDS read base pointers (aP0/aP1/bP0/bP1, XOR keys
// folded in) precomputed once; tile loop unrolled x2 so double-buffer parity
// is compile-time -> all ds_read addresses are base + imm offset (max 47104 B
// < 64 KiB). Read pattern identical to round 4 (same banks, zero conflicts);
// only the per-tile address VALU is removed.
// =================================================================================
#define WAIT_VM(N) asm volatile("s_waitcnt vmcnt(" #N ")" ::: "memory")
#define BAR        asm volatile("s_barrier" ::: "memory")

template <int BUF, int QM>
__device__ __forceinline__ void ldA16(const ushort* aP0, const ushort* aP1,
                                      half8 (&af)[4][2]) {
#pragma unroll
    for (int mi = 0; mi < 4; mi++) {
        af[mi][0] = *(const half8*)(aP0 + BUF * 16384 + QM * 4096 + mi * 1024);
        af[mi][1] = *(const half8*)(aP1 + BUF * 16384 + QM * 4096 + mi * 1024);
    }
}
template <int BUF, int QN>
__device__ __forceinline__ void ldB16(const ushort* bP0, const ushort* bP1,
                                      half8 (&bf)[2][2]) {
#pragma unroll
    for (int ni = 0; ni < 2; ni++) {
        bf[ni][0] = *(const half8*)(bP0 + BUF * 16384 + QN * 2048 + ni * 1024);
        bf[ni][1] = *(const half8*)(bP1 + BUF * 16384 + QN * 2048 + ni * 1024);
    }
}
template <int QM, int QN>
__device__ __forceinline__ void mma(const half8 (&af)[4][2], const half8 (&bf)[2][2],
                                    f32x4 (&acc)[8][4]) {
    __builtin_amdgcn_s_setprio(1);
#pragma unroll
    for (int mi = 0; mi < 4; mi++)
#pragma unroll
        for (int ni = 0; ni < 2; ni++) {
            f32x4 c = acc[QM * 4 + mi][QN * 2 + ni];
            c = __builtin_amdgcn_mfma_f32_16x16x32_f16(af[mi][0], bf[ni][0], c, 0, 0, 0);
            c = __builtin_amdgcn_mfma_f32_16x16x32_f16(af[mi][1], bf[ni][1], c, 0, 0, 0);
            acc[QM * 4 + mi][QN * 2 + ni] = c;
        }
    __builtin_amdgcn_s_setprio(0);
}

// One K-tile: X { vm(4)[A(t) landed] BAR | read af0(t) | stage A(t+1) |
//                 mma q10(t-1) }
//             Y { vm(4)[B(t) landed] BAR | mma q11(t-1) | read bf0,bf1(t) |
//                 stage B(t+1) | read af1(t) | mma q00(t) q01(t) }
#define TILE_STEP(T_, BUF_, STG_, LASTY_, DOPREV_)                      \
    {                                                                   \
        WAIT_VM(4);                                                     \
        BAR;                                                            \
        ldA16<BUF_, 0>(aP0, aP1, af0);                                  \
        if (STG_) { stA((T_) + 1, 0); stA((T_) + 1, 1); }               \
        if (DOPREV_) mma<1, 0>(af1, bf0, acc);                          \
        if (LASTY_) { WAIT_VM(0); } else { WAIT_VM(4); }                \
        BAR;                                                            \
        if (DOPREV_) mma<1, 1>(af1, bf1, acc);                          \
        ldB16<BUF_, 0>(bP0, bP1, bf0);                                  \
        ldB16<BUF_, 1>(bP0, bP1, bf1);                                  \
        if (STG_) { stB((T_) + 1, 0); stB((T_) + 1, 1); }               \
        ldA16<BUF_, 1>(aP0, aP1, af1);                                  \
        mma<0, 0>(af0, bf0, acc);                                       \
        mma<0, 1>(af0, bf1, acc);                                       \
    }

template <bool HALF_OUT>
__global__ __launch_bounds__(512, 1) void gemm256(const ushort* __restrict__ A,
                                                  const ushort* __restrict__ B,
                                                  void* __restrict__ Cv,
                                                  int M, int N, int K, float alpha,
                                                  size_t sA, size_t sB, size_t sC) {
    __shared__ __align__(16) ushort As[2][256][64];   // 64 KB
    __shared__ __align__(16) ushort Bs[2][256][64];   // 64 KB

    A += (size_t)blockIdx.z * sA;
    B += (size_t)blockIdx.z * sB;

    // T1: bijective XCD swizzle over the flattened 2D grid (nwg % 8 == 0 always here)
    const int nwg  = gridDim.x * gridDim.y;
    const int orig = blockIdx.y * gridDim.x + blockIdx.x;
    const int wg   = (orig & 7) * (nwg >> 3) + (orig >> 3);
    const int bm   = (wg / gridDim.x) * 256;
    const int bn   = (wg % gridDim.x) * 256;

    const int tid  = threadIdx.x;
    const int lane = tid & 63;
    const int wave = tid >> 6;     // 0..7
    const int wr   = wave >> 2;    // 0..1 -> 128-row half
    const int wc   = wave & 3;     // 0..3 -> 64-col slice
    const int col  = lane & 15;
    const int quad = lane >> 4;

    // ---- staging: chunk = tid (rows 0..63 of half) and tid+512 (rows 64..127).
    // Inverse-swizzled global source: row r keeps its row, 16B-col = (c&7) ^ (r&7).
    const int srow = tid >> 3;                           // 0..63
    const int scol = ((tid & 7) ^ (srow & 7)) * 8;       // swizzled 16B column (elems)
    const ushort* gA = A + (size_t)(bm + srow) * K + scol;
    const ushort* gB = B + (size_t)(bn + srow) * K + scol;
    const size_t rs64  = (size_t)64 * K;
    const size_t rs128 = (size_t)128 * K;
    ushort* lA = &As[0][0][0] + tid * 8;                 // linear dest, byte tid*16
    ushort* lB = &Bs[0][0][0] + tid * 8;

    auto stA = [&](int t, int h) {
        const ushort* s = gA + (size_t)t * 64 + (h ? rs128 : (size_t)0);
        ushort* d = lA + ((t & 1) << 14) + (h << 13);
        gld_lds16(s, d);
        gld_lds16(s + rs64, d + 4096);
    };
    auto stB = [&](int t, int h) {
        const ushort* s = gB + (size_t)t * 64 + (h ? rs128 : (size_t)0);
        ushort* d = lB + ((t & 1) << 14) + (h << 13);
        gld_lds16(s, d);
        gld_lds16(s + rs64, d + 4096);
    };

    // ---- precomputed per-lane LDS read base pointers (swizzle folded in):
    // offset = row*64 + ((ksl*4+quad)^(col&7))*8 ushorts; BUF/QM/QN/mi/ni via imm.
    const int kx0   = ((quad ^ (col & 7)) * 8);
    const int kx1   = (((4 + quad) ^ (col & 7)) * 8);
    const ushort* aP0 = &As[0][0][0] + (wr * 128 + col) * 64 + kx0;
    const ushort* aP1 = &As[0][0][0] + (wr * 128 + col) * 64 + kx1;
    const ushort* bP0 = &Bs[0][0][0] + (wc * 64 + col) * 64 + kx0;
    const ushort* bP1 = &Bs[0][0][0] + (wc * 64 + col) * 64 + kx1;

    f32x4 acc[8][4];
#pragma unroll
    for (int i = 0; i < 8; i++)
#pragma unroll
        for (int j = 0; j < 4; j++) { f32x4 z = {0.f, 0.f, 0.f, 0.f}; acc[i][j] = z; }

    half8 af0[4][2], af1[4][2], bf0[2][2], bf1[2][2];

    const int T  = K >> 6;   // K-tiles (K = 2048 or 4096 -> T = 32 or 64, even)
    const int TP = T >> 1;

    // prologue: issue tile-0 staging (A first, then B -- wait order relies on this)
    stA(0, 0); stA(0, 1); stB(0, 0); stB(0, 1);

    for (int p = 0; p < TP; ++p) {
        const int t0 = 2 * p;
        TILE_STEP(t0,     0, true,       false,       t0 > 0);
        TILE_STEP(t0 + 1, 1, p + 1 < TP, p + 1 == TP, true);
    }
    // drain last tile's second A-half quadrants
    mma<1, 0>(af1, bf0, acc);
    mma<1, 1>(af1, bf1, acc);

    // ---- epilogue: C/D layout col = lane&15, row = quad*4 + r [m89/m91]
    ushort* Ch = (ushort*)Cv + (size_t)blockIdx.z * sC;
    float*  Cf = (float*)Cv + (size_t)blockIdx.z * sC;
#pragma unroll
    for (int qm = 0; qm < 2; qm++)
#pragma unroll
        for (int mi = 0; mi < 4; mi++)
#pragma unroll
            for (int qn = 0; qn < 2; qn++)
#pragma unroll
                for (int ni = 0; ni < 2; ni++)
#pragma unroll
                    for (int r = 0; r < 4; r++) {
                        int grow = bm + wr * 128 + qm * 64 + mi * 16 + quad * 4 + r;
                        int gcol = bn + wc * 64 + qn * 32 + ni * 16 + col;
                        float val = alpha * acc[qm * 4 + mi][qn * 2 + ni][r];
                        if (HALF_OUT)
                            Ch[(size_t)grow * N + gcol] = f2h(val);
                        else
                            Cf[(size_t)grow * N + gcol] = val;
                    }
}

// ---------------- RoPE: f16 q,k in; interleaved f16 q_rot/k_rot + fp32 k_rot ------
__global__ __launch_bounds__(256) void rope_kernel(const ushort* __restrict__ qh,
                                                   const ushort* __restrict__ kh,
                                                   const float* __restrict__ cosT,
                                                   const float* __restrict__ sinT,
                                                   const int* __restrict__ pos,
                                                   ushort* __restrict__ qr,
                                                   ushort* __restrict__ kr,
                                                   float* __restrict__ krf32) {
    int idx = blockIdx.x * 256 + threadIdx.x;       // B*S*(D2/4) total
    int row = idx >> 8;                             // D2_/4 == 256
    int jj  = (idx & 255) * 4;
    int p = pos[row & (S_ - 1)];
    const ushort* q = qh + (size_t)row * H_ + jj;
    const ushort* k = kh + (size_t)row * H_ + jj;
    const float* cr = cosT + (size_t)p * D2_ + jj;
    const float* sr = sinT + (size_t)p * D2_ + jj;
    float4 c = *(const float4*)cr;
    float4 sn = *(const float4*)sr;
    ushort4 qr4 = *(const ushort4*)q;
    ushort4 qi4 = *(const ushort4*)(q + D2_);
    ushort4 kr4 = *(const ushort4*)k;
    ushort4 ki4 = *(const ushort4*)(k + D2_);

    float qrv[4] = {h2f(qr4.x), h2f(qr4.y), h2f(qr4.z), h2f(qr4.w)};
    float qiv[4] = {h2f(qi4.x), h2f(qi4.y), h2f(qi4.z), h2f(qi4.w)};
    float krv[4] = {h2f(kr4.x), h2f(kr4.y), h2f(kr4.z), h2f(kr4.w)};
    float kiv[4] = {h2f(ki4.x), h2f(ki4.y), h2f(ki4.z), h2f(ki4.w)};
    float cv[4] = {c.x, c.y, c.z, c.w};
    float sv[4] = {sn.x, sn.y, sn.z, sn.w};

    ushort qo[8], ko[8];
    float kf[8];
#pragma unroll
    for (int t = 0; t < 4; t++) {
        float o0 = qrv[t] * cv[t] - qiv[t] * sv[t];
        float o1 = qrv[t] * sv[t] + qiv[t] * cv[t];
        qo[2 * t] = f2h(o0); qo[2 * t + 1] = f2h(o1);
        float p0 = krv[t] * cv[t] - kiv[t] * sv[t];
        float p1 = krv[t] * sv[t] + kiv[t] * cv[t];
        ko[2 * t] = f2h(p0); ko[2 * t + 1] = f2h(p1);
        kf[2 * t] = p0; kf[2 * t + 1] = p1;
    }
    ushort* qro = qr + (size_t)row * H_ + 2 * jj;
    ushort* kro = kr + (size_t)row * H_ + 2 * jj;
    float* krf  = krf32 + (size_t)row * H_ + 2 * jj;
    *(ushort4*)(qro)     = *(ushort4*)(qo);
    *(ushort4*)(qro + 4) = *(ushort4*)(qo + 4);
    *(ushort4*)(kro)     = *(ushort4*)(ko);
    *(ushort4*)(kro + 4) = *(ushort4*)(ko + 4);
    *(float4*)(krf)      = *(float4*)(kf);
    *(float4*)(krf + 4)  = *(float4*)(kf + 4);
}

// ---------------- transpose+cast: v[b][s][h] fp32 -> vt[b][h][s] f16 ------------
__global__ __launch_bounds__(256) void transpose_cast_kernel(const float* __restrict__ v,
                                                             ushort* __restrict__ vt) {
    __shared__ float tile[32][33];
    int b  = blockIdx.z;
    int s0 = blockIdx.y * 32, h0 = blockIdx.x * 32;
    const float* vb = v + (size_t)b * S_ * H_;
    ushort* vtb = vt + (size_t)b * H_ * S_;
    int tx = threadIdx.x & 31, ty = threadIdx.x >> 5;
#pragma unroll
    for (int i = 0; i < 32; i += 8)
        tile[ty + i][tx] = vb[(size_t)(s0 + ty + i) * H_ + h0 + tx];
    __syncthreads();
#pragma unroll
    for (int i = 0; i < 32; i += 8)
        vtb[(size_t)(h0 + ty + i) * S_ + s0 + tx] = f2h(tile[tx][ty + i]);
}

// ---------------- row softmax: f16 scores (4096 wide) -> f16 probs --------------
__global__ __launch_bounds__(256) void softmax_kernel(const ushort* __restrict__ sc,
                                                      ushort* __restrict__ pr) {
    __shared__ float red[8];
    size_t row = blockIdx.x;
    const uint4* r = (const uint4*)(sc + row * (size_t)S_);   // 512 x 16B per row
    int tid = threadIdx.x;
    uint4 v0 = r[tid], v1 = r[tid + 256];
    uint w[8] = {v0.x, v0.y, v0.z, v0.w, v1.x, v1.y, v1.z, v1.w};
    float f[16];
#pragma unroll
    for (int i = 0; i < 8; i++) {
        f[2 * i]     = h2f((ushort)(w[i] & 0xffffu));
        f[2 * i + 1] = h2f((ushort)(w[i] >> 16));
    }
    float m = -1e30f;
#pragma unroll
    for (int i = 0; i < 16; i++) m = fmaxf(m, f[i]);
#pragma unroll
    for (int off = 32; off >= 1; off >>= 1) m = fmaxf(m, __shfl_xor(m, off));
    if ((tid & 63) == 0) red[tid >> 6] = m;
    __syncthreads();
    m = fmaxf(fmaxf(red[0], red[1]), fmaxf(red[2], red[3]));
    float s = 0.f;
#pragma unroll
    for (int i = 0; i < 16; i++) { f[i] = __expf(f[i] - m); s += f[i]; }
#pragma unroll
    for (int off = 32; off >= 1; off >>= 1) s += __shfl_xor(s, off);
    if ((tid & 63) == 0) red[4 + (tid >> 6)] = s;
    __syncthreads();
    float inv = 1.0f / (red[4] + red[5] + red[6] + red[7]);
    uint o[8];
#pragma unroll
    for (int i = 0; i < 8; i++)
        o[i] = (uint)f2h(f[2 * i] * inv) | ((uint)f2h(f[2 * i + 1] * inv) << 16);
    uint4* op = (uint4*)(pr + row * (size_t)S_);
    uint4 u0, u1;
    u0.x = o[0]; u0.y = o[1]; u0.z = o[2]; u0.w = o[3];
    u1.x = o[4]; u1.y = o[5]; u1.z = o[6]; u1.w = o[7];
    op[tid] = u0;
    op[tid + 256] = u1;
}

// =================================================================================
extern "C" void kernel_launch(void* const* d_in, const int* in_sizes, int n_in,
                              void* d_out, int out_size, void* d_ws, size_t ws_size,
                              hipStream_t stream) {
    const float* hs   = (const float*)d_in[0];
    const float* wq   = (const float*)d_in[1];
    const float* wk   = (const float*)d_in[2];
    const float* wv   = (const float*)d_in[3];
    const float* wo   = (const float*)d_in[4];
    const float* fcos = (const float*)d_in[5];
    const float* fsin = (const float*)d_in[6];
    const int*   pos  = (const int*)d_in[7];

    const size_t BSH = (size_t)B_ * S_ * H_;   // 16,777,216
    const size_t HH  = (size_t)H_ * H_;        //  4,194,304

    float* out      = (float*)d_out;           // [0] output (B,S,H)
    float* krot_out = out + BSH;               // [1] k_rot  (B,S,H)
    float* v_out    = krot_out + BSH;          // [2] v      (B,S,H)

    char* ws = (char*)d_ws;
    const size_t MB = 1ull << 20;
    ushort* Xb  = (ushort*)(ws + 0);
    ushort* Wqb = (ushort*)(ws + 32 * MB);
    ushort* Wkb = (ushort*)(ws + 40 * MB);
    ushort* Wvb = (ushort*)(ws + 48 * MB);
    ushort* Wob = (ushort*)(ws + 56 * MB);
    ushort* qh  = (ushort*)(ws + 64 * MB);
    ushort* kh  = (ushort*)(ws + 96 * MB);
    ushort* qrb = (ushort*)(ws + 128 * MB);
    ushort* krb = (ushort*)(ws + 160 * MB);
    ushort* vtb = (ushort*)(ws + 192 * MB);
    ushort* sc  = (ushort*)(ws + 224 * MB);    // f16 scores (67 MB)
    ushort* prb = (ushort*)(ws + 64 * MB);     // reuse qh+kh (dead after rope)
    ushort* cb  = (ushort*)(ws + 128 * MB);    // reuse qrb (dead after scores)

    // 1. casts to f16
    cast_f16_kernel<<<(int)(BSH / 4 / 256), 256, 0, stream>>>(hs, Xb, (int)(BSH / 4));
    cast4_f16_kernel<<<dim3((int)(HH / 4 / 256), 4), 256, 0, stream>>>(
        wq, wk, wv, wo, Wqb, Wkb, Wvb, Wob, (int)(HH / 4));

    // 2. Q/K/V projections (C = X * W^T); Q/K straight to f16, V to fp32 output
    dim3 gProj(H_ / 256, (B_ * S_) / 256, 1);  // (8, 32) = 256 blocks
    gemm256<true ><<<gProj, 512, 0, stream>>>(Xb, Wqb, qh,    B_ * S_, H_, H_, 1.0f, 0, 0, 0);
    gemm256<true ><<<gProj, 512, 0, stream>>>(Xb, Wkb, kh,    B_ * S_, H_, H_, 1.0f, 0, 0, 0);
    gemm256<false><<<gProj, 512, 0, stream>>>(Xb, Wvb, v_out, B_ * S_, H_, H_, 1.0f, 0, 0, 0);

    // 3. RoPE (f16 q_rot/k_rot for attention + fp32 k_rot output)
    rope_kernel<<<(B_ * S_ * (D2_ / 4)) / 256, 256, 0, stream>>>(
        qh, kh, fcos, fsin, pos, qrb, krb, krot_out);

    // 4. v^T in f16 for the PV GEMM
    transpose_cast_kernel<<<dim3(H_ / 32, S_ / 32, B_), 256, 0, stream>>>(v_out, vtb);

    // 5. scores = SCALE * q_rot k_rot^T, f16 out, both batches in one launch (z)
    dim3 gSc(S_ / 256, S_ / 256, B_);          // (16, 16, 2)
    gemm256<true><<<gSc, 512, 0, stream>>>(qrb, krb, sc, S_, S_, H_, SCALE_,
                                           (size_t)S_ * H_, (size_t)S_ * H_,
                                           (size_t)S_ * S_);

    // 6. softmax rows (f16 in) -> f16 probs
    softmax_kernel<<<B_ * S_, 256, 0, stream>>>(sc, prb);

    // 7. ctx = probs @ v (as probs * (v^T)^T), f16 out, both batches via z
    dim3 gPV(H_ / 256, S_ / 256, B_);          // (8, 16, 2) = 256 blocks
    gemm256<true><<<gPV, 512, 0, stream>>>(prb, vtb, cb, S_, H_, S_, 1.0f,
                                           (size_t)S_ * S_, (size_t)H_ * S_,
                                           (size_t)S_ * H_);

    // 8. output projection
    gemm256<false><<<gProj, 512, 0, stream>>>(cb, Wob, out, B_ * S_, H_, H_, 1.0f, 0, 0, 0);
}

// Round 8
// 1070.065 us; speedup vs baseline: 1.0397x; 1.0061x over previous
//
#include <hip/hip_runtime.h>
#include <cstdint>
#include <cstddef>

// Problem constants (from reference)
#define B_    2
#define S_    4096
#define H_    2048
#define D2_   1024
#define SCALE_ 0.125f

typedef __attribute__((ext_vector_type(8))) _Float16 half8;
typedef __attribute__((ext_vector_type(4))) float f32x4;

__device__ __forceinline__ ushort f2h(float f) {
    _Float16 h = (_Float16)f;
    return *(ushort*)&h;
}
__device__ __forceinline__ float h2f(ushort u) {
    return (float)(*(_Float16*)&u);
}

// async 16B global -> LDS (wave-uniform base + lane*16 semantics)
__device__ __forceinline__ void gld_lds16(const ushort* g, ushort* l) {
    __builtin_amdgcn_global_load_lds((const __attribute__((address_space(1))) void*)g,
                                     (__attribute__((address_space(3))) void*)l,
                                     16, 0, 0);
}

// ---------------- elementwise cast fp32 -> fp16, n4 = n/4 ----------------
__global__ __launch_bounds__(256) void cast_f16_kernel(const float* __restrict__ src,
                                                       ushort* __restrict__ dst, int n4) {
    int i = blockIdx.x * 256 + threadIdx.x;
    if (i < n4) {
        float4 v = ((const float4*)src)[i];
        ushort4 o;
        o.x = f2h(v.x); o.y = f2h(v.y); o.z = f2h(v.z); o.w = f2h(v.w);
        ((ushort4*)dst)[i] = o;
    }
}

__global__ __launch_bounds__(256) void cast4_f16_kernel(const float* __restrict__ w0,
                                                        const float* __restrict__ w1,
                                                        const float* __restrict__ w2,
                                                        const float* __restrict__ w3,
                                                        ushort* __restrict__ o0,
                                                        ushort* __restrict__ o1,
                                                        ushort* __restrict__ o2,
                                                        ushort* __restrict__ o3,
                                                        int n4) {
    int i = blockIdx.x * 256 + threadIdx.x;
    if (i >= n4) return;
    const float* s; ushort* d;
    switch (blockIdx.y) {
        case 0: s = w0; d = o0; break;
        case 1: s = w1; d = o1; break;
        case 2: s = w2; d = o2; break;
        default: s = w3; d = o3; break;
    }
    float4 v = ((const float4*)s)[i];
    ushort4 o;
    o.x = f2h(v.x); o.y = f2h(v.y); o.z = f2h(v.z); o.w = f2h(v.w);
    ((ushort4*)d)[i] = o;
}

// =================================================================================
// gemm256: C[M,N] = alpha * A[M,K] * B[N,K]^T, f16 in, f32/f16 out.
// Round-4 verified core + round-7 pointer precompute (VALUBusy 12%, 0 bank
// conflicts): 256x256 tile, BK=64, 8 waves (2Mx4N), 16x16x32 f16 MFMA, X/Y
// two-region schedule (2 barriers + 2 counted vmcnt(4) per K-tile), staging
// one tile ahead via global_load_lds, XOR-swizzled LDS (T2), setprio (T5),
// XCD swizzle (T1).
// NEW (round 8): HALF_OUT epilogue stages C through LDS (As/Bs dead after
// K-loop; merged into one 128KB smem) and writes 16B/lane fully-coalesced
// 512B row segments. Direct 2B scatter stores (32B per 16-lane group) caused
// line-granular RMW: WRITE 291MB for a 67MB payload (rounds 5+7). fp32 path
// keeps direct stores (full 64B sectors, proven clean in round 4).
// =================================================================================
#define WAIT_VM(N) asm volatile("s_waitcnt vmcnt(" #N ")" ::: "memory")
#define BAR        asm volatile("s_barrier" ::: "memory")

template <int BUF, int QM>
__device__ __forceinline__ void ldA16(const ushort* aP0, const ushort* aP1,
                                      half8 (&af)[4][2]) {
#pragma unroll
    for (int mi = 0; mi < 4; mi++) {
        af[mi][0] = *(const half8*)(aP0 + BUF * 16384 + QM * 4096 + mi * 1024);
        af[mi][1] = *(const half8*)(aP1 + BUF * 16384 + QM * 4096 + mi * 1024);
    }
}
template <int BUF, int QN>
__device__ __forceinline__ void ldB16(const ushort* bP0, const ushort* bP1,
                                      half8 (&bf)[2][2]) {
#pragma unroll
    for (int ni = 0; ni < 2; ni++) {
        bf[ni][0] = *(const half8*)(bP0 + BUF * 16384 + QN * 2048 + ni * 1024);
        bf[ni][1] = *(const half8*)(bP1 + BUF * 16384 + QN * 2048 + ni * 1024);
    }
}
template <int QM, int QN>
__device__ __forceinline__ void mma(const half8 (&af)[4][2], const half8 (&bf)[2][2],
                                    f32x4 (&acc)[8][4]) {
    __builtin_amdgcn_s_setprio(1);
#pragma unroll
    for (int mi = 0; mi < 4; mi++)
#pragma unroll
        for (int ni = 0; ni < 2; ni++) {
            f32x4 c = acc[QM * 4 + mi][QN * 2 + ni];
            c = __builtin_amdgcn_mfma_f32_16x16x32_f16(af[mi][0], bf[ni][0], c, 0, 0, 0);
            c = __builtin_amdgcn_mfma_f32_16x16x32_f16(af[mi][1], bf[ni][1], c, 0, 0, 0);
            acc[QM * 4 + mi][QN * 2 + ni] = c;
        }
    __builtin_amdgcn_s_setprio(0);
}

// One K-tile: X { vm(4)[A(t) landed] BAR | read af0(t) | stage A(t+1) |
//                 mma q10(t-1) }
//             Y { vm(4)[B(t) landed] BAR | mma q11(t-1) | read bf0,bf1(t) |
//                 stage B(t+1) | read af1(t) | mma q00(t) q01(t) }
#define TILE_STEP(T_, BUF_, STG_, LASTY_, DOPREV_)                      \
    {                                                                   \
        WAIT_VM(4);                                                     \
        BAR;                                                            \
        ldA16<BUF_, 0>(aP0, aP1, af0);                                  \
        if (STG_) { stA((T_) + 1, 0); stA((T_) + 1, 1); }               \
        if (DOPREV_) mma<1, 0>(af1, bf0, acc);                          \
        if (LASTY_) { WAIT_VM(0); } else { WAIT_VM(4); }                \
        BAR;                                                            \
        if (DOPREV_) mma<1, 1>(af1, bf1, acc);                          \
        ldB16<BUF_, 0>(bP0, bP1, bf0);                                  \
        ldB16<BUF_, 1>(bP0, bP1, bf1);                                  \
        if (STG_) { stB((T_) + 1, 0); stB((T_) + 1, 1); }               \
        ldA16<BUF_, 1>(aP0, aP1, af1);                                  \
        mma<0, 0>(af0, bf0, acc);                                       \
        mma<0, 1>(af0, bf1, acc);                                       \
    }

template <bool HALF_OUT>
__global__ __launch_bounds__(512, 1) void gemm256(const ushort* __restrict__ A,
                                                  const ushort* __restrict__ B,
                                                  void* __restrict__ Cv,
                                                  int M, int N, int K, float alpha,
                                                  size_t sA, size_t sB, size_t sC) {
    // As = smem[0:32768) = [2][256][64]; Bs = smem[32768:65536); 128 KiB total.
    // After the K-loop the whole buffer is reused as the C staging tile.
    __shared__ __align__(16) ushort smem[65536];

    A += (size_t)blockIdx.z * sA;
    B += (size_t)blockIdx.z * sB;

    // T1: bijective XCD swizzle over the flattened 2D grid (nwg % 8 == 0 always here)
    const int nwg  = gridDim.x * gridDim.y;
    const int orig = blockIdx.y * gridDim.x + blockIdx.x;
    const int wg   = (orig & 7) * (nwg >> 3) + (orig >> 3);
    const int bm   = (wg / gridDim.x) * 256;
    const int bn   = (wg % gridDim.x) * 256;

    const int tid  = threadIdx.x;
    const int lane = tid & 63;
    const int wave = tid >> 6;     // 0..7
    const int wr   = wave >> 2;    // 0..1 -> 128-row half
    const int wc   = wave & 3;     // 0..3 -> 64-col slice
    const int col  = lane & 15;
    const int quad = lane >> 4;

    // ---- staging: chunk = tid (rows 0..63 of half) and tid+512 (rows 64..127).
    // Inverse-swizzled global source: row r keeps its row, 16B-col = (c&7) ^ (r&7).
    const int srow = tid >> 3;                           // 0..63
    const int scol = ((tid & 7) ^ (srow & 7)) * 8;       // swizzled 16B column (elems)
    const ushort* gA = A + (size_t)(bm + srow) * K + scol;
    const ushort* gB = B + (size_t)(bn + srow) * K + scol;
    const size_t rs64  = (size_t)64 * K;
    const size_t rs128 = (size_t)128 * K;
    ushort* lA = smem + tid * 8;                         // linear dest, byte tid*16
    ushort* lB = smem + 32768 + tid * 8;

    auto stA = [&](int t, int h) {
        const ushort* s = gA + (size_t)t * 64 + (h ? rs128 : (size_t)0);
        ushort* d = lA + ((t & 1) << 14) + (h << 13);
        gld_lds16(s, d);
        gld_lds16(s + rs64, d + 4096);
    };
    auto stB = [&](int t, int h) {
        const ushort* s = gB + (size_t)t * 64 + (h ? rs128 : (size_t)0);
        ushort* d = lB + ((t & 1) << 14) + (h << 13);
        gld_lds16(s, d);
        gld_lds16(s + rs64, d + 4096);
    };

    // ---- precomputed per-lane LDS read base pointers (swizzle folded in):
    // offset = row*64 + ((ksl*4+quad)^(col&7))*8 ushorts; BUF/QM/QN/mi/ni via imm.
    const int kx0   = ((quad ^ (col & 7)) * 8);
    const int kx1   = (((4 + quad) ^ (col & 7)) * 8);
    const ushort* aP0 = smem + (wr * 128 + col) * 64 + kx0;
    const ushort* aP1 = smem + (wr * 128 + col) * 64 + kx1;
    const ushort* bP0 = smem + 32768 + (wc * 64 + col) * 64 + kx0;
    const ushort* bP1 = smem + 32768 + (wc * 64 + col) * 64 + kx1;

    f32x4 acc[8][4];
#pragma unroll
    for (int i = 0; i < 8; i++)
#pragma unroll
        for (int j = 0; j < 4; j++) { f32x4 z = {0.f, 0.f, 0.f, 0.f}; acc[i][j] = z; }

    half8 af0[4][2], af1[4][2], bf0[2][2], bf1[2][2];

    const int T  = K >> 6;   // K-tiles (K = 2048 or 4096 -> T = 32 or 64, even)
    const int TP = T >> 1;

    // prologue: issue tile-0 staging (A first, then B -- wait order relies on this)
    stA(0, 0); stA(0, 1); stB(0, 0); stB(0, 1);

    for (int p = 0; p < TP; ++p) {
        const int t0 = 2 * p;
        TILE_STEP(t0,     0, true,       false,       t0 > 0);
        TILE_STEP(t0 + 1, 1, p + 1 < TP, p + 1 == TP, true);
    }
    // drain last tile's second A-half quadrants
    mma<1, 0>(af1, bf0, acc);
    mma<1, 1>(af1, bf1, acc);

    if (HALF_OUT) {
        // ---- LDS-staged coalesced f16 epilogue ----
        BAR;   // all waves done reading the last tile's LDS
        ushort* CL = smem;   // [256][256] f16 C tile, XOR-chunk swizzled per row
#pragma unroll
        for (int qm = 0; qm < 2; qm++)
#pragma unroll
            for (int mi = 0; mi < 4; mi++)
#pragma unroll
                for (int qn = 0; qn < 2; qn++)
#pragma unroll
                    for (int ni = 0; ni < 2; ni++)
#pragma unroll
                        for (int r = 0; r < 4; r++) {
                            int lrow = wr * 128 + qm * 64 + mi * 16 + quad * 4 + r;
                            int lcol = wc * 64 + qn * 32 + ni * 16 + col;
                            int ch   = (lcol >> 3) ^ (lrow & 7);
                            CL[lrow * 256 + ch * 8 + (lcol & 7)] =
                                f2h(alpha * acc[qm * 4 + mi][qn * 2 + ni][r]);
                        }
        BAR;   // deposits visible
        ushort* Ch = (ushort*)Cv + (size_t)blockIdx.z * sC;
#pragma unroll
        for (int i = 0; i < 16; i++) {
            int idx = i * 512 + tid;
            int row = idx >> 5;          // 0..255
            int c   = idx & 31;          // 16B chunk within row
            int cc  = c ^ (row & 7);
            uint4 v = *(const uint4*)(CL + row * 256 + cc * 8);
            *(uint4*)(Ch + (size_t)(bm + row) * N + bn + c * 8) = v;
        }
    } else {
        // ---- direct fp32 stores: 16 lanes x 4B = full 64B sector (round-4 proven)
        float* Cf = (float*)Cv + (size_t)blockIdx.z * sC;
#pragma unroll
        for (int qm = 0; qm < 2; qm++)
#pragma unroll
            for (int mi = 0; mi < 4; mi++)
#pragma unroll
                for (int qn = 0; qn < 2; qn++)
#pragma unroll
                    for (int ni = 0; ni < 2; ni++)
#pragma unroll
                        for (int r = 0; r < 4; r++) {
                            int grow = bm + wr * 128 + qm * 64 + mi * 16 + quad * 4 + r;
                            int gcol = bn + wc * 64 + qn * 32 + ni * 16 + col;
                            Cf[(size_t)grow * N + gcol] =
                                alpha * acc[qm * 4 + mi][qn * 2 + ni][r];
                        }
    }
}

// ---------------- RoPE: f16 q,k in; interleaved f16 q_rot/k_rot + fp32 k_rot ------
__global__ __launch_bounds__(256) void rope_kernel(const ushort* __restrict__ qh,
                                                   const ushort* __restrict__ kh,
                                                   const float* __restrict__ cosT,
                                                   const float* __restrict__ sinT,
                                                   const int* __restrict__ pos,
                                                   ushort* __restrict__ qr,
                                                   ushort* __restrict__ kr,
                                                   float* __restrict__ krf32) {
    int idx = blockIdx.x * 256 + threadIdx.x;       // B*S*(D2/4) total
    int row = idx >> 8;                             // D2_/4 == 256
    int jj  = (idx & 255) * 4;
    int p = pos[row & (S_ - 1)];
    const ushort* q = qh + (size_t)row * H_ + jj;
    const ushort* k = kh + (size_t)row * H_ + jj;
    const float* cr = cosT + (size_t)p * D2_ + jj;
    const float* sr = sinT + (size_t)p * D2_ + jj;
    float4 c = *(const float4*)cr;
    float4 sn = *(const float4*)sr;
    ushort4 qr4 = *(const ushort4*)q;
    ushort4 qi4 = *(const ushort4*)(q + D2_);
    ushort4 kr4 = *(const ushort4*)k;
    ushort4 ki4 = *(const ushort4*)(k + D2_);

    float qrv[4] = {h2f(qr4.x), h2f(qr4.y), h2f(qr4.z), h2f(qr4.w)};
    float qiv[4] = {h2f(qi4.x), h2f(qi4.y), h2f(qi4.z), h2f(qi4.w)};
    float krv[4] = {h2f(kr4.x), h2f(kr4.y), h2f(kr4.z), h2f(kr4.w)};
    float kiv[4] = {h2f(ki4.x), h2f(ki4.y), h2f(ki4.z), h2f(ki4.w)};
    float cv[4] = {c.x, c.y, c.z, c.w};
    float sv[4] = {sn.x, sn.y, sn.z, sn.w};

    ushort qo[8], ko[8];
    float kf[8];
#pragma unroll
    for (int t = 0; t < 4; t++) {
        float o0 = qrv[t] * cv[t] - qiv[t] * sv[t];
        float o1 = qrv[t] * sv[t] + qiv[t] * cv[t];
        qo[2 * t] = f2h(o0); qo[2 * t + 1] = f2h(o1);
        float p0 = krv[t] * cv[t] - kiv[t] * sv[t];
        float p1 = krv[t] * sv[t] + kiv[t] * cv[t];
        ko[2 * t] = f2h(p0); ko[2 * t + 1] = f2h(p1);
        kf[2 * t] = p0; kf[2 * t + 1] = p1;
    }
    ushort* qro = qr + (size_t)row * H_ + 2 * jj;
    ushort* kro = kr + (size_t)row * H_ + 2 * jj;
    float* krf  = krf32 + (size_t)row * H_ + 2 * jj;
    *(ushort4*)(qro)     = *(ushort4*)(qo);
    *(ushort4*)(qro + 4) = *(ushort4*)(qo + 4);
    *(ushort4*)(kro)     = *(ushort4*)(ko);
    *(ushort4*)(kro + 4) = *(ushort4*)(ko + 4);
    *(float4*)(krf)      = *(float4*)(kf);
    *(float4*)(krf + 4)  = *(float4*)(kf + 4);
}

// ---------------- transpose+cast: v[b][s][h] fp32 -> vt[b][h][s] f16 ------------
__global__ __launch_bounds__(256) void transpose_cast_kernel(const float* __restrict__ v,
                                                             ushort* __restrict__ vt) {
    __shared__ float tile[32][33];
    int b  = blockIdx.z;
    int s0 = blockIdx.y * 32, h0 = blockIdx.x * 32;
    const float* vb = v + (size_t)b * S_ * H_;
    ushort* vtb = vt + (size_t)b * H_ * S_;
    int tx = threadIdx.x & 31, ty = threadIdx.x >> 5;
#pragma unroll
    for (int i = 0; i < 32; i += 8)
        tile[ty + i][tx] = vb[(size_t)(s0 + ty + i) * H_ + h0 + tx];
    __syncthreads();
#pragma unroll
    for (int i = 0; i < 32; i += 8)
        vtb[(size_t)(h0 + ty + i) * S_ + s0 + tx] = f2h(tile[tx][ty + i]);
}

// ---------------- row softmax: f16 scores (4096 wide) -> f16 probs --------------
__global__ __launch_bounds__(256) void softmax_kernel(const ushort* __restrict__ sc,
                                                      ushort* __restrict__ pr) {
    __shared__ float red[8];
    size_t row = blockIdx.x;
    const uint4* r = (const uint4*)(sc + row * (size_t)S_);   // 512 x 16B per row
    int tid = threadIdx.x;
    uint4 v0 = r[tid], v1 = r[tid + 256];
    uint w[8] = {v0.x, v0.y, v0.z, v0.w, v1.x, v1.y, v1.z, v1.w};
    float f[16];
#pragma unroll
    for (int i = 0; i < 8; i++) {
        f[2 * i]     = h2f((ushort)(w[i] & 0xffffu));
        f[2 * i + 1] = h2f((ushort)(w[i] >> 16));
    }
    float m = -1e30f;
#pragma unroll
    for (int i = 0; i < 16; i++) m = fmaxf(m, f[i]);
#pragma unroll
    for (int off = 32; off >= 1; off >>= 1) m = fmaxf(m, __shfl_xor(m, off));
    if ((tid & 63) == 0) red[tid >> 6] = m;
    __syncthreads();
    m = fmaxf(fmaxf(red[0], red[1]), fmaxf(red[2], red[3]));
    float s = 0.f;
#pragma unroll
    for (int i = 0; i < 16; i++) { f[i] = __expf(f[i] - m); s += f[i]; }
#pragma unroll
    for (int off = 32; off >= 1; off >>= 1) s += __shfl_xor(s, off);
    if ((tid & 63) == 0) red[4 + (tid >> 6)] = s;
    __syncthreads();
    float inv = 1.0f / (red[4] + red[5] + red[6] + red[7]);
    uint o[8];
#pragma unroll
    for (int i = 0; i < 8; i++)
        o[i] = (uint)f2h(f[2 * i] * inv) | ((uint)f2h(f[2 * i + 1] * inv) << 16);
    uint4* op = (uint4*)(pr + row * (size_t)S_);
    uint4 u0, u1;
    u0.x = o[0]; u0.y = o[1]; u0.z = o[2]; u0.w = o[3];
    u1.x = o[4]; u1.y = o[5]; u1.z = o[6]; u1.w = o[7];
    op[tid] = u0;
    op[tid + 256] = u1;
}

// =================================================================================
extern "C" void kernel_launch(void* const* d_in, const int* in_sizes, int n_in,
                              void* d_out, int out_size, void* d_ws, size_t ws_size,
                              hipStream_t stream) {
    const float* hs   = (const float*)d_in[0];
    const float* wq   = (const float*)d_in[1];
    const float* wk   = (const float*)d_in[2];
    const float* wv   = (const float*)d_in[3];
    const float* wo   = (const float*)d_in[4];
    const float* fcos = (const float*)d_in[5];
    const float* fsin = (const float*)d_in[6];
    const int*   pos  = (const int*)d_in[7];

    const size_t BSH = (size_t)B_ * S_ * H_;   // 16,777,216
    const size_t HH  = (size_t)H_ * H_;        //  4,194,304

    float* out      = (float*)d_out;           // [0] output (B,S,H)
    float* krot_out = out + BSH;               // [1] k_rot  (B,S,H)
    float* v_out    = krot_out + BSH;          // [2] v      (B,S,H)

    char* ws = (char*)d_ws;
    const size_t MB = 1ull << 20;
    ushort* Xb  = (ushort*)(ws + 0);
    ushort* Wqb = (ushort*)(ws + 32 * MB);
    ushort* Wkb = (ushort*)(ws + 40 * MB);
    ushort* Wvb = (ushort*)(ws + 48 * MB);
    ushort* Wob = (ushort*)(ws + 56 * MB);
    ushort* qh  = (ushort*)(ws + 64 * MB);
    ushort* kh  = (ushort*)(ws + 96 * MB);
    ushort* qrb = (ushort*)(ws + 128 * MB);
    ushort* krb = (ushort*)(ws + 160 * MB);
    ushort* vtb = (ushort*)(ws + 192 * MB);
    ushort* sc  = (ushort*)(ws + 224 * MB);    // f16 scores (67 MB)
    ushort* prb = (ushort*)(ws + 64 * MB);     // reuse qh+kh (dead after rope)
    ushort* cb  = (ushort*)(ws + 128 * MB);    // reuse qrb (dead after scores)

    // 1. casts to f16
    cast_f16_kernel<<<(int)(BSH / 4 / 256), 256, 0, stream>>>(hs, Xb, (int)(BSH / 4));
    cast4_f16_kernel<<<dim3((int)(HH / 4 / 256), 4), 256, 0, stream>>>(
        wq, wk, wv, wo, Wqb, Wkb, Wvb, Wob, (int)(HH / 4));

    // 2. Q/K/V projections (C = X * W^T); Q/K straight to f16, V to fp32 output
    dim3 gProj(H_ / 256, (B_ * S_) / 256, 1);  // (8, 32) = 256 blocks
    gemm256<true ><<<gProj, 512, 0, stream>>>(Xb, Wqb, qh,    B_ * S_, H_, H_, 1.0f, 0, 0, 0);
    gemm256<true ><<<gProj, 512, 0, stream>>>(Xb, Wkb, kh,    B_ * S_, H_, H_, 1.0f, 0, 0, 0);
    gemm256<false><<<gProj, 512, 0, stream>>>(Xb, Wvb, v_out, B_ * S_, H_, H_, 1.0f, 0, 0, 0);

    // 3. RoPE (f16 q_rot/k_rot for attention + fp32 k_rot output)
    rope_kernel<<<(B_ * S_ * (D2_ / 4)) / 256, 256, 0, stream>>>(
        qh, kh, fcos, fsin, pos, qrb, krb, krot_out);

    // 4. v^T in f16 for the PV GEMM
    transpose_cast_kernel<<<dim3(H_ / 32, S_ / 32, B_), 256, 0, stream>>>(v_out, vtb);

    // 5. scores = SCALE * q_rot k_rot^T, f16 out, both batches in one launch (z)
    dim3 gSc(S_ / 256, S_ / 256, B_);          // (16, 16, 2)
    gemm256<true><<<gSc, 512, 0, stream>>>(qrb, krb, sc, S_, S_, H_, SCALE_,
                                           (size_t)S_ * H_, (size_t)S_ * H_,
                                           (size_t)S_ * S_);

    // 6. softmax rows (f16 in) -> f16 probs
    softmax_kernel<<<B_ * S_, 256, 0, stream>>>(sc, prb);

    // 7. ctx = probs @ v (as probs * (v^T)^T), f16 out, both batches via z
    dim3 gPV(H_ / 256, S_ / 256, B_);          // (8, 16, 2) = 256 blocks
    gemm256<true><<<gPV, 512, 0, stream>>>(prb, vtb, cb, S_, H_, S_, 1.0f,
                                           (size_t)S_ * S_, (size_t)H_ * S_,
                                           (size_t)S_ * H_);

    // 8. output projection
    gemm256<false><<<gProj, 512, 0, stream>>>(cb, Wob, out, B_ * S_, H_, H_, 1.0f, 0, 0, 0);
}